// Round 6
// baseline (96.263 us; speedup 1.0000x reference)
//
#include <hip/hip_runtime.h>
#include <cstdint>

// ---------------------------------------------------------------------------
// QuantumBranch, R9: two kernels again — V/G/g/C0 via SGPR (s_load) path,
// DS ops cut 320 -> ~34 per wave.
// R8 post-mortem: rocprof finally caught qb_fused: 47-55us, HBM 18%,
// VALUBusy 12%, Occ 20% — NO pipe near roofline => dependent-latency bound.
// ~320 DS instr/wave (256 uniform ds_read_b128 in matvec + store exchange +
// setup shfls) x ~120cyc with only 2-4 waves/SIMD and VGPR=60 (no prefetch
// depth) ~= the whole 47us. The kernel has been ~47us since R3; every
// structural tweak was a 1-3us nibble around an untouched latency core.
//
// R9: setup kernel (R3's verified one, bit-identical) writes V^T + LN
// constants to d_ws (global). Main kernel reads V/G/g/C0 with UNIFORM
// addresses -> compiler emits s_load into SGPRs (SMEM pipe, hoistable;
// v_fma takes one SGPR operand). Matvec = pure VALU, zero LDS. Only DS
// left: wave-local q/inv exchange for coalesced stores (34 ops, all
// prefetchable with the freed VGPR headroom). 1024 blocks, 4 blocks/CU.
// All FMA orders bit-identical to R8 -> absmax stays exactly 0.015625.
//
// Math (verified R1-R8): circuit collapses to V = U*diag((-i)^popc),
// z_w = sum_i +/- (r_i^2+s_i^2), r=Re(V)m, s=Im(V)m, m = product-state
// magnitudes from tanh(x)*pi/2. LayerNorm collapses to a 4x4 quadratic
// form: out[b,k] = inv_b*(A[k].q_b + B0[k]) + beta[k].
// ---------------------------------------------------------------------------

// ws float offsets (global workspace)
#define WS_VRT 0     // 256: Re(V)^T  [col*16+row]
#define WS_VIT 256   // 256: Im(V)^T
#define WS_A   512   // 256: (W-colmean)*gamma  [k*4+w]
#define WS_B0  768   // 64:  (b-bmean)*gamma
#define WS_G   832   // 16:  G[4][4]
#define WS_g   848   // 4
#define WS_C0  852   // 1

// One wave, no barriers. lane = row*4 + cg; lane holds U[row][4cg..4cg+3].
__global__ __launch_bounds__(64) void qb_setup(const float* __restrict__ wts,
                                               const float* __restrict__ W,
                                               const float* __restrict__ bias,
                                               const float* __restrict__ gamma,
                                               float* __restrict__ ws) {
    const int lane = threadIdx.x;
    const int row  = lane >> 2;
    const int cg   = lane & 3;

    float ur[4], ui[4];   // U[row][4cg+c]
    #pragma unroll
    for (int c = 0; c < 4; ++c) {
        ur[c] = (row == 4*cg + c) ? 1.f : 0.f;
        ui[c] = 0.f;
    }

    #pragma unroll
    for (int l = 0; l < 2; ++l) {
        // Rot on wires 0..3 (wire0 = MSB of row index)
        #pragma unroll
        for (int w = 0; w < 4; ++w) {
            const float ph = wts[l*12 + w*3 + 0];
            const float th = wts[l*12 + w*3 + 1];
            const float om = wts[l*12 + w*3 + 2];
            float st, ct; __sincosf(0.5f*th, &st, &ct);
            float sp, cp; __sincosf(0.5f*(ph+om), &sp, &cp);
            float sm, cm; __sincosf(0.5f*(ph-om), &sm, &cm);
            const float a00r =  cp*ct, a00i = -sp*ct;
            const float a01r = -cm*st, a01i = -sm*st;
            const float a10r =  cm*st, a10i = -sm*st;
            const float a11r =  cp*ct, a11i =  sp*ct;
            const int m8 = 8 >> w;
            const int xm = m8 << 2;            // lane xor mask for row^m8
            const bool hi = (row & m8) != 0;
            #pragma unroll
            for (int c = 0; c < 4; ++c) {
                const float pr = __shfl_xor(ur[c], xm, 64);
                const float pi = __shfl_xor(ui[c], xm, 64);
                float nr, ni;
                if (!hi) {
                    nr = a00r*ur[c] - a00i*ui[c] + a01r*pr - a01i*pi;
                    ni = a00r*ui[c] + a00i*ur[c] + a01r*pi + a01i*pr;
                } else {
                    nr = a11r*ur[c] - a11i*ui[c] + a10r*pr - a10i*pi;
                    ni = a11r*ui[c] + a11i*ur[c] + a10r*pi + a10i*pr;
                }
                ur[c] = nr; ui[c] = ni;
            }
        }
        // CNOT ring, range r = l%3+1: new[row] = old[src(row)]
        const int rr = (l == 0) ? 1 : 2;
        #pragma unroll
        for (int w = 0; w < 4; ++w) {
            const int cmk = 8 >> w;
            const int tmk = 8 >> ((w + rr) & 3);
            const int src = (row & cmk) ? (row ^ tmk) : row;
            const int srcLane = src*4 + cg;
            #pragma unroll
            for (int c = 0; c < 4; ++c) {
                ur[c] = __shfl(ur[c], srcLane, 64);
                ui[c] = __shfl(ui[c], srcLane, 64);
            }
        }
    }

    // V = U * diag((-i)^popc); store transposed: ws[VRT + col*16 + row]
    #pragma unroll
    for (int c = 0; c < 4; ++c) {
        const int col = 4*cg + c;
        const int p = __popc(col) & 3;
        float vr, vi;
        if (p == 0)      { vr =  ur[c]; vi =  ui[c]; }
        else if (p == 1) { vr =  ui[c]; vi = -ur[c]; }
        else if (p == 2) { vr = -ur[c]; vi = -ui[c]; }
        else             { vr = -ui[c]; vi =  ur[c]; }
        ws[WS_VRT + col*16 + row] = vr;
        ws[WS_VIT + col*16 + row] = vi;
    }

    // Projection / layernorm constants: lane k
    {
        const int k = lane;
        float w0 = W[k*4+0], w1 = W[k*4+1], w2 = W[k*4+2], w3 = W[k*4+3];
        float bk = bias[k];
        auto wsum = [](float v) {
            #pragma unroll
            for (int o = 32; o; o >>= 1) v += __shfl_xor(v, o, 64);
            return v;
        };
        const float inv64 = 1.f/64.f;
        const float m0 = wsum(w0)*inv64, m1 = wsum(w1)*inv64;
        const float m2 = wsum(w2)*inv64, m3 = wsum(w3)*inv64;
        const float bm = wsum(bk)*inv64;
        float cc[4] = {w0-m0, w1-m1, w2-m2, w3-m3};
        const float bc = bk - bm;
        const float gk = gamma[k];
        #pragma unroll
        for (int w = 0; w < 4; ++w) ws[WS_A + k*4 + w] = cc[w]*gk;
        ws[WS_B0 + k] = bc*gk;
        #pragma unroll
        for (int a = 0; a < 4; ++a)
            #pragma unroll
            for (int b2 = a; b2 < 4; ++b2) {
                const float s = wsum(cc[a]*cc[b2])*inv64;
                if (k == 0) {
                    ws[WS_G + a*4 + b2] = s;
                    ws[WS_G + b2*4 + a] = s;
                }
            }
        #pragma unroll
        for (int a = 0; a < 4; ++a) {
            const float s = wsum(bc*cc[a])*inv64;
            if (k == 0) ws[WS_g + a] = s;
        }
        {
            const float s = wsum(bc*bc)*inv64;
            if (k == 0) ws[WS_C0] = s;
        }
    }
}

__global__ __launch_bounds__(256, 4) void qb_main(const float* __restrict__ x,
                                                  const float* __restrict__ beta,
                                                  const float* __restrict__ ws,
                                                  float* __restrict__ out) {
    // tiny LDS: only the wave-local q/inv exchange for coalesced stores
    __shared__ __align__(16) float4 sq[256];
    __shared__ float sinv[256];

    const int tid  = threadIdx.x;
    const int wv   = tid >> 6;
    const int lane = tid & 63;

    // issue all VMEM loads up front: x (per-sample), A/B0/beta (L2-hot)
    const int sample = blockIdx.x * 256 + tid;
    const float4 xv = ((const float4*)x)[sample];
    const int k4t = lane & 15;
    float4 A4[4];
    #pragma unroll
    for (int u = 0; u < 4; ++u) A4[u] = ((const float4*)(ws + WS_A))[k4t*4 + u];
    const float4 B04v = ((const float4*)(ws + WS_B0))[k4t];
    const float4 Bt4v = ((const float4*)beta)[k4t];

    // ---- product-state magnitudes m[16] (pure VALU) ----
    float m[16];
    {
        const float xa[4] = {xv.x, xv.y, xv.z, xv.w};
        float c4[4], s4[4];
        #pragma unroll
        for (int w = 0; w < 4; ++w) {
            const float h = tanhf(xa[w]) * 1.5707963267948966f;
            __sincosf(h, &s4[w], &c4[w]);
        }
        const float e01[4] = {c4[0]*c4[1], c4[0]*s4[1], s4[0]*c4[1], s4[0]*s4[1]};
        const float e23[4] = {c4[2]*c4[3], c4[2]*s4[3], s4[2]*c4[3], s4[2]*s4[3]};
        #pragma unroll
        for (int j = 0; j < 16; ++j) m[j] = e01[j>>2]*e23[j&3];
    }

    // ---- matvec: V via UNIFORM loads -> s_load/SGPR; zero LDS traffic ----
    // FMA order identical to R6/R7/R8 (i ascending inside j ascending).
    float r[16], si[16];
    #pragma unroll
    for (int i = 0; i < 16; ++i) { r[i] = 0.f; si[i] = 0.f; }
    #pragma unroll
    for (int j = 0; j < 16; ++j) {
        const float mj = m[j];
        #pragma unroll
        for (int i = 0; i < 16; ++i) {
            r[i]  = fmaf(ws[WS_VRT + j*16 + i], mj, r[i]);
            si[i] = fmaf(ws[WS_VIT + j*16 + i], mj, si[i]);
        }
    }

    // ---- finish: z -> softmax -> var -> inv (G/g/C0 uniform -> SGPR) ----
    float z0 = 0.f, z1 = 0.f, z2 = 0.f, z3 = 0.f;
    #pragma unroll
    for (int i = 0; i < 16; ++i) {
        const float p = r[i]*r[i] + si[i]*si[i];
        z0 += (i & 8) ? -p : p;
        z1 += (i & 4) ? -p : p;
        z2 += (i & 2) ? -p : p;
        z3 += (i & 1) ? -p : p;
    }
    const float mx = fmaxf(fmaxf(z0, z1), fmaxf(z2, z3));
    const float e0 = __expf(z0-mx), e1 = __expf(z1-mx);
    const float e2 = __expf(z2-mx), e3 = __expf(z3-mx);
    const float rs = 1.f / (e0+e1+e2+e3);
    const float qx = e0*rs, qy = e1*rs, qz = e2*rs, qw = e3*rs;

    float var = ws[WS_C0];
    {
        const float qa[4] = {qx, qy, qz, qw};
        #pragma unroll
        for (int a = 0; a < 4; ++a) {
            float t = 2.f * ws[WS_g + a];
            #pragma unroll
            for (int b2 = 0; b2 < 4; ++b2) t = fmaf(ws[WS_G + a*4 + b2], qa[b2], t);
            var = fmaf(qa[a], t, var);
        }
    }
    const float inv = rsqrtf(var + 1e-5f);

    // ---- stage q/inv wave-locally (same-wave RAW ordered by lgkmcnt) ----
    sq[wv*64 + lane]   = make_float4(qx, qy, qz, qw);
    sinv[wv*64 + lane] = inv;

    // ---- coalesced store phase: 16 iters, wave-local LDS broadcast ----
    const float B04[4] = {B04v.x, B04v.y, B04v.z, B04v.w};
    const float Bt4[4] = {Bt4v.x, Bt4v.y, Bt4v.z, Bt4v.w};
    float4* outv = (float4*)out + (size_t)blockIdx.x * 4096 + wv * 1024 + lane;
    const float4* qld = sq + wv*64 + (lane >> 4);
    const float*  ild = sinv + wv*64 + (lane >> 4);
    #pragma unroll
    for (int iter = 0; iter < 16; ++iter) {
        const float4 q  = qld[iter*4];     // 4 addrs/wave, conflict-free
        const float  iv = ild[iter*4];
        float4 o;
        float* op = (float*)&o;
        #pragma unroll
        for (int u = 0; u < 4; ++u) {
            float t = B04[u];
            t = fmaf(A4[u].x, q.x, t);
            t = fmaf(A4[u].y, q.y, t);
            t = fmaf(A4[u].z, q.z, t);
            t = fmaf(A4[u].w, q.w, t);
            op[u] = fmaf(t, iv, Bt4[u]);
        }
        outv[iter*64] = o;
    }
}

extern "C" void kernel_launch(void* const* d_in, const int* in_sizes, int n_in,
                              void* d_out, int out_size, void* d_ws, size_t ws_size,
                              hipStream_t stream) {
    const float* x     = (const float*)d_in[0];
    const float* wts   = (const float*)d_in[1];
    const float* W     = (const float*)d_in[2];
    const float* bias  = (const float*)d_in[3];
    const float* gamma = (const float*)d_in[4];
    const float* beta  = (const float*)d_in[5];
    float* out = (float*)d_out;
    float* ws  = (float*)d_ws;
    const int B = in_sizes[0] / 4;   // 262144

    hipLaunchKernelGGL(qb_setup, dim3(1), dim3(64), 0, stream, wts, W, bias, gamma, ws);
    hipLaunchKernelGGL(qb_main, dim3(B / 256), dim3(256), 0, stream, x, beta, ws, out);
}